// Round 9
// baseline (365.143 us; speedup 1.0000x reference)
//
#include <hip/hip_runtime.h>
#include <hip/hip_bf16.h>
#include <math.h>

#define HF 128          // hidden / input feature dim
#define GCOUNT 64       // graphs in batch
#define OUTF 64         // final output features
#define NEG 0.2f        // leaky relu slope
#define CH 2048         // edges per partition block
#define BCAP 8192       // per-bucket edge capacity (expected ~4340, +50 sigma)

typedef unsigned short u16;
typedef unsigned int   u32;
typedef unsigned char  u8;
typedef short bf16x8 __attribute__((ext_vector_type(8)));
typedef float f32x4  __attribute__((ext_vector_type(4)));

// fp32 -> bf16 (RNE) bit trick
__device__ __forceinline__ u16 f2b(float f) {
    u32 u = __builtin_bit_cast(u32, f);
    u32 r = (u + 0x7FFFu + ((u >> 16) & 1u)) >> 16;
    return (u16)r;
}
__device__ __forceinline__ float blo(u32 u) { return __builtin_bit_cast(float, u << 16); }
__device__ __forceinline__ float bhi(u32 u) { return __builtin_bit_cast(float, u & 0xFFFF0000u); }

// ---- custom fp8 e4m3 codec (no denormals; |v|<2^-7 flushes to 0; RNE) ----
// encode: byte = s | (E4M3 code). decode is the exact inverse on the code set.
__device__ __forceinline__ u8 f2q(float f) {
    u32 u = __builtin_bit_cast(u32, f);
    u32 s = (u >> 24) & 0x80u;
    u32 mag = u & 0x7FFFFFFFu;
    u32 r = mag + 0x7FFFFu + ((mag >> 20) & 1u);   // RNE to 3-bit mantissa
    int t = (int)(r >> 20) - 0x3C0;                // exp bias shift (127-7)<<3
    t = t < 0 ? 0 : (t > 127 ? 127 : t);
    return (u8)(s | (u32)t);
}
__device__ __forceinline__ float q2f(u32 b) {
    u32 t = b & 0x7Fu;
    u32 bits = ((t << 20) + 0x3C000000u) | ((b & 0x80u) << 24);
    return t ? __builtin_bit_cast(float, bits) : 0.0f;
}

// ======================= fused pack + init =======================
// blocks 0..31: pack 4 weight matrices into MFMA B-frag order
//   P[m][(t*4+kc)*64+lane][j] = bf16(W_m[kc*32+quad*8+j][16t+(lane&15)])
// block 32: init bucketCur; blocks 33..64: zero pooled
__global__ void k_pack_init(const float* __restrict__ W0, const float* __restrict__ Wl,
                            u16* __restrict__ P, int* bucketCur, float* pooled) {
    if (blockIdx.x < 32) {
        int m = blockIdx.x >> 3;                       // 0..3: W0, Wl[0..2]
        int i = (blockIdx.x & 7) * 256 + threadIdx.x;  // 0..2047
        const float* W = (m == 0) ? W0 : Wl + (size_t)(m - 1) * HF * HF;
        u16* Pm = P + (size_t)m * HF * HF;
        int lane = i & 63, kc = (i >> 6) & 3, t = i >> 8;
        int quad = lane >> 4, col = 16 * t + (lane & 15);
        #pragma unroll
        for (int j = 0; j < 8; ++j) {
            int k = kc * 32 + quad * 8 + j;
            Pm[(size_t)i * 8 + j] = f2b(W[k * HF + col]);
        }
    } else if (blockIdx.x == 32) {
        bucketCur[threadIdx.x] = threadIdx.x * BCAP;
    } else {
        pooled[(blockIdx.x - 33) * 256 + threadIdx.x] = 0.f;
    }
}

// ======================= bucketed CSR build (fixed-capacity buckets) =======================
// bucket b = dst >> 8; bucket region = [b*BCAP, b*BCAP + cnt_b).

// single pass: LDS hist -> chunk reservation -> packed scatter (src<<8 | dst&255)
__global__ __launch_bounds__(256) void k_bpart(const int* __restrict__ esrc,
                                               const int* __restrict__ edst,
                                               int* __restrict__ bucketCur,
                                               u32* __restrict__ epart, int ne, int ntot) {
    __shared__ int cnt[256];
    __shared__ int base[256];
    int t0 = blockIdx.x * CH, t1 = min(t0 + CH, ntot);
    cnt[threadIdx.x] = 0;
    __syncthreads();
    for (int t = t0 + threadIdx.x; t < t1; t += 256) {
        int d = (t < ne) ? edst[t] : t - ne;       // tail = self loops
        atomicAdd(&cnt[d >> 8], 1);
    }
    __syncthreads();
    int c = cnt[threadIdx.x];
    base[threadIdx.x] = c ? atomicAdd(&bucketCur[threadIdx.x], c) : 0;
    cnt[threadIdx.x] = 0;
    __syncthreads();
    for (int t = t0 + threadIdx.x; t < t1; t += 256) {
        int s, d;
        if (t < ne) { s = esrc[t]; d = edst[t]; }
        else        { s = t - ne; d = s; }
        int b = d >> 8;
        int pos = base[b] + atomicAdd(&cnt[b], 1);
        epart[pos] = ((u32)s << 8) | (u32)(d & 255);
    }
}

// one block per bucket: local degree hist + scan -> rowbeg/rowend + colidx scatter
__global__ __launch_bounds__(256) void k_bcsr(const u32* __restrict__ epart,
                                              const int* __restrict__ bucketCur,
                                              int* __restrict__ rowbeg,
                                              int* __restrict__ rowend,
                                              int* __restrict__ colidx, int n) {
    __shared__ int deg[256], offs[256], curs[256], s[256];
    int b = blockIdx.x, tid = threadIdx.x;
    int e0 = b * BCAP, e1 = bucketCur[b];
    deg[tid] = 0;
    curs[tid] = 0;
    __syncthreads();
    for (int t = e0 + tid; t < e1; t += 256)
        atomicAdd(&deg[epart[t] & 255u], 1);
    __syncthreads();
    int v = deg[tid];
    s[tid] = v;
    __syncthreads();
    int acc = v;
    for (int off = 1; off < 256; off <<= 1) {
        int t = (tid >= off) ? s[tid - off] : 0;
        __syncthreads();
        acc += t;
        s[tid] = acc;
        __syncthreads();
    }
    int excl = acc - v;
    offs[tid] = excl;
    int node = (b << 8) + tid;
    if (node < n) {
        rowbeg[node] = e0 + excl;
        rowend[node] = e0 + excl + v;
    }
    __syncthreads();
    for (int t = e0 + tid; t < e1; t += 256) {
        u32 e = epart[t];
        int l = e & 255u;
        int pos = e0 + offs[l] + atomicAdd(&curs[l], 1);
        colidx[pos] = (int)(e >> 8);
    }
}

// ======================= MFMA GEMM (+bias, + optional fused alpha dots) ==========
// block = 256 (4 waves); wave w owns rows m0+16w..+15, all 128 cols (8 n-tiles).
// C/D layout: col = lane&15 (in tile), row = quad*4 + reg
// Q8: write fp8 output (layer hp); else bf16 output.
template<bool A32, bool Q8>
__global__ __launch_bounds__(256) void k_gemm_mfma(const u16* __restrict__ Ab,
                                                   const float* __restrict__ Af,
                                                   const u16* __restrict__ Bp,
                                                   const float* __restrict__ bias,
                                                   const float* __restrict__ a_s,
                                                   const float* __restrict__ a_d,
                                                   float* __restrict__ as_,
                                                   float* __restrict__ ad_,
                                                   u16* __restrict__ C,
                                                   u8* __restrict__ C8, int M) {
    int lane = threadIdx.x & 63;
    int wave = threadIdx.x >> 6;
    int quad = lane >> 4, l16 = lane & 15;
    int m0 = blockIdx.x * 64 + wave * 16;
    int arow = m0 + l16;
    bool aval = arow < M;
    const bf16x8* Av = A32 ? nullptr : (const bf16x8*)(Ab + (size_t)arow * HF);
    const bf16x8* Bv = (const bf16x8*)Bp;
    f32x4 acc[8] = {};

    #pragma unroll
    for (int kc = 0; kc < 4; ++kc) {
        bf16x8 a = {};
        if (aval) {
            if constexpr (A32) {
                const float* ap = Af + (size_t)arow * HF + kc * 32 + quad * 8;
                float4 f0 = *(const float4*)ap;
                float4 f1 = *(const float4*)(ap + 4);
                a[0] = (short)f2b(f0.x); a[1] = (short)f2b(f0.y);
                a[2] = (short)f2b(f0.z); a[3] = (short)f2b(f0.w);
                a[4] = (short)f2b(f1.x); a[5] = (short)f2b(f1.y);
                a[6] = (short)f2b(f1.z); a[7] = (short)f2b(f1.w);
            } else {
                a = Av[kc * 4 + quad];
            }
        }
        #pragma unroll
        for (int t = 0; t < 8; ++t)
            acc[t] = __builtin_amdgcn_mfma_f32_16x16x32_bf16(a, Bv[t * 256 + kc * 64 + lane],
                                                             acc[t], 0, 0, 0);
    }

    int orow0 = m0 + quad * 4;
    #pragma unroll
    for (int t = 0; t < 8; ++t) {
        float b4 = bias ? bias[t * 16 + l16] : 0.f;
        #pragma unroll
        for (int r = 0; r < 4; ++r) {
            int orow = orow0 + r;
            if (orow < M) {
                float v = acc[t][r] + b4;
                if constexpr (Q8) C8[(size_t)orow * HF + t * 16 + l16] = f2q(v);
                else              C [(size_t)orow * HF + t * 16 + l16] = f2b(v);
            }
        }
    }

    // fused attention dots (fp32 accumulators -> exact attention weights)
    if (as_) {
        float avs[8], avd[8];
        #pragma unroll
        for (int t = 0; t < 8; ++t) {
            avs[t] = a_s[t * 16 + l16];
            avd[t] = a_d[t * 16 + l16];
        }
        #pragma unroll
        for (int r = 0; r < 4; ++r) {
            float ps = 0.f, pd = 0.f;
            #pragma unroll
            for (int t = 0; t < 8; ++t) {
                ps = fmaf(acc[t][r], avs[t], ps);
                pd = fmaf(acc[t][r], avd[t], pd);
            }
            #pragma unroll
            for (int o = 1; o < 16; o <<= 1) {
                ps += __shfl_xor(ps, o);
                pd += __shfl_xor(pd, o);
            }
            int row = orow0 + r;
            if (l16 == 0 && row < M) { as_[row] = ps; ad_[row] = pd; }
        }
    }
}

// ======================= per-dst softmax aggregation (fp8 gather) ==========
// Pass 2: half-wave per edge (32 lanes x 4B = one 128B fp8 row), 2 edges per
// load group, unroll x4. Halves combined via shfl_xor(32).
__global__ __launch_bounds__(256) void k_agg(const int* __restrict__ rowbeg,
                                             const int* __restrict__ rowend,
                                             const int* __restrict__ colidx,
                                             const u8* __restrict__ hp8,
                                             const float* __restrict__ as_,
                                             const float* __restrict__ ad_,
                                             const float* __restrict__ bl,
                                             u16* __restrict__ hout,
                                             int n, int relu) {
    int wave = (blockIdx.x * 256 + threadIdx.x) >> 6;
    int lane = threadIdx.x & 63;
    if (wave >= n) return;
    int beg = rowbeg[wave], end = rowend[wave];
    int deg = end - beg;
    float adi = ad_[wave];

    // lane t owns edge t (first 64)
    int  srcl = (lane < deg) ? colidx[beg + lane] : 0;
    float el = -1e30f;
    if (lane < deg) {
        float e = as_[srcl] + adi;
        el = e > 0.f ? e : NEG * e;
    }

    float m = el;
    for (int jj = beg + 64 + lane; jj < end; jj += 64) {
        float e = as_[colidx[jj]] + adi;
        e = e > 0.f ? e : NEG * e;
        m = fmaxf(m, e);
    }
    #pragma unroll
    for (int off = 32; off; off >>= 1) m = fmaxf(m, __shfl_xor(m, off));

    float ex = (lane < deg) ? __expf(el - m) : 0.f;
    float ssum = ex;
    for (int jj = beg + 64 + lane; jj < end; jj += 64) {
        float e = as_[colidx[jj]] + adi;
        e = e > 0.f ? e : NEG * e;
        ssum += __expf(e - m);
    }
    #pragma unroll
    for (int off = 32; off; off >>= 1) ssum += __shfl_xor(ssum, off);
    float inv = 1.f / ssum;
    float wl = ex * inv;        // this lane's edge weight

    // ---- pass 2 ----
    int hl = lane & 31;         // feature group: feats hl*4 .. hl*4+3
    int half = lane >> 5;       // which edge of the pair this half-wave takes
    float a0 = 0.f, a1 = 0.f, a2 = 0.f, a3 = 0.f;
    int cnt = deg < 64 ? deg : 64;
    int npair = (cnt + 1) >> 1;

    int p = 0;
    for (; p + 4 <= npair; p += 4) {
        #pragma unroll
        for (int i = 0; i < 4; ++i) {
            int e  = 2 * (p + i) + half;
            int ec = e < cnt ? e : cnt - 1;
            int   s = __shfl(srcl, ec);
            float w = (e < cnt) ? __shfl(wl, ec) : 0.f;
            u32 v = ((const u32*)(hp8 + (size_t)s * HF))[hl];
            a0 = fmaf(w, q2f(v & 0xFFu), a0);
            a1 = fmaf(w, q2f((v >> 8) & 0xFFu), a1);
            a2 = fmaf(w, q2f((v >> 16) & 0xFFu), a2);
            a3 = fmaf(w, q2f(v >> 24), a3);
        }
    }
    for (; p < npair; ++p) {
        int e  = 2 * p + half;
        int ec = e < cnt ? e : cnt - 1;
        int   s = __shfl(srcl, ec);
        float w = (e < cnt) ? __shfl(wl, ec) : 0.f;
        u32 v = ((const u32*)(hp8 + (size_t)s * HF))[hl];
        a0 = fmaf(w, q2f(v & 0xFFu), a0);
        a1 = fmaf(w, q2f((v >> 8) & 0xFFu), a1);
        a2 = fmaf(w, q2f((v >> 16) & 0xFFu), a2);
        a3 = fmaf(w, q2f(v >> 24), a3);
    }
    // rare deg>64 tail: half 0 only (avoids double count after combine)
    for (int jj = beg + 64; jj < end; ++jj) {
        int srcn = colidx[jj];
        float e = as_[srcn] + adi;
        e = e > 0.f ? e : NEG * e;
        float w = (half == 0) ? __expf(e - m) * inv : 0.f;
        u32 v = ((const u32*)(hp8 + (size_t)srcn * HF))[hl];
        a0 = fmaf(w, q2f(v & 0xFFu), a0);
        a1 = fmaf(w, q2f((v >> 8) & 0xFFu), a1);
        a2 = fmaf(w, q2f((v >> 16) & 0xFFu), a2);
        a3 = fmaf(w, q2f(v >> 24), a3);
    }

    // combine halves
    a0 += __shfl_xor(a0, 32); a1 += __shfl_xor(a1, 32);
    a2 += __shfl_xor(a2, 32); a3 += __shfl_xor(a3, 32);

    if (half == 0) {
        float4 bb = ((const float4*)bl)[hl];
        a0 += bb.x; a1 += bb.y; a2 += bb.z; a3 += bb.w;
        if (relu) {
            a0 = fmaxf(a0, 0.f); a1 = fmaxf(a1, 0.f);
            a2 = fmaxf(a2, 0.f); a3 = fmaxf(a3, 0.f);
        }
        uint2 o;
        o.x = ((u32)f2b(a1) << 16) | (u32)f2b(a0);
        o.y = ((u32)f2b(a3) << 16) | (u32)f2b(a2);
        ((uint2*)(hout + (size_t)wave * HF))[hl] = o;
    }
}

// ======================= pooling over sorted batch (bf16 h, fp32 accum) ==========
#define PROWS 128
__global__ __launch_bounds__(128) void k_pool(const u16* __restrict__ hb,
                                              const int* __restrict__ batch,
                                              float* __restrict__ pooled, int n) {
    int r0 = blockIdx.x * PROWS;
    int r1 = min(r0 + PROWS, n);
    if (r0 >= r1) return;
    int t = threadIdx.x;
    int cur = batch[r0];
    float acc = 0.f;
    for (int i = r0; i < r1; ++i) {
        int b = batch[i];
        if (b != cur) {
            atomicAdd(&pooled[cur * HF + t], acc);
            acc = 0.f;
            cur = b;
        }
        acc += __builtin_bit_cast(float, (u32)hb[(size_t)i * HF + t] << 16);
    }
    atomicAdd(&pooled[cur * HF + t], acc);
}

__global__ void k_final(const float* __restrict__ pooled, const float* __restrict__ Wf,
                        const float* __restrict__ bf, float* __restrict__ out) {
    int g = blockIdx.x, o = threadIdx.x;   // 64 threads
    float acc = bf[o];
    #pragma unroll 8
    for (int k = 0; k < HF; ++k) acc = fmaf(pooled[g * HF + k], Wf[k * OUTF + o], acc);
    out[g * OUTF + o] = acc;
}

// ======================= launch =======================
extern "C" void kernel_launch(void* const* d_in, const int* in_sizes, int n_in,
                              void* d_out, int out_size, void* d_ws, size_t ws_size,
                              hipStream_t stream) {
    const float* x      = (const float*)d_in[0];
    const int*   edge   = (const int*)d_in[1];
    const int*   batch  = (const int*)d_in[2];
    const float* W0     = (const float*)d_in[3];
    const float* b0     = (const float*)d_in[4];
    const float* Wl     = (const float*)d_in[5];
    const float* a_src  = (const float*)d_in[6];
    const float* a_dst  = (const float*)d_in[7];
    const float* bl     = (const float*)d_in[8];
    const float* Wf     = (const float*)d_in[9];
    const float* bf     = (const float*)d_in[10];
    float* out = (float*)d_out;

    const int N  = in_sizes[2];
    const int E  = in_sizes[1] / 2;
    const int Et = E + N;
    const int L  = 3;
    const int NB = (N + 255) >> 8;               // buckets (<= 256)

    char* ws = (char*)d_ws;
    size_t off = 0;
    auto alloc = [&](size_t bytes) { char* p = ws + off; off += (bytes + 255) & ~(size_t)255; return p; };
    u16*   hb      = (u16*)alloc((size_t)N * HF * 2);
    u8*    hp8     = (u8*)alloc((size_t)N * HF);
    u16*   Wp      = (u16*)alloc((size_t)4 * HF * HF * 2);
    float* as_     = (float*)alloc((size_t)N * 4);
    float* ad_     = (float*)alloc((size_t)N * 4);
    int*   rowbeg  = (int*)alloc((size_t)N * 4);
    int*   rowend  = (int*)alloc((size_t)N * 4);
    int*   colidx  = (int*)alloc((size_t)NB * BCAP * 4);
    u32*   epart   = (u32*)alloc((size_t)NB * BCAP * 4);
    int*   bucketCur = (int*)alloc(256 * 4);
    float* pooled  = (float*)alloc((size_t)GCOUNT * HF * 4);
    (void)ws_size; (void)n_in; (void)out_size;

    const int wb4   = (N + 3) / 4;               // wave-per-node kernels
    const int gemmb = (N + 63) / 64;
    const int partb = (Et + CH - 1) / CH;

    const int* esrc = edge;
    const int* edst = edge + E;

    // --- pack weights + init bucketCur + zero pooled (one launch) ---
    k_pack_init<<<65, 256, 0, stream>>>(W0, Wl, Wp, bucketCur, pooled);

    // --- bucketed dst-CSR build (reused across all 3 layers) ---
    k_bpart<<<partb, 256, 0, stream>>>(esrc, edst, bucketCur, epart, E, Et);
    k_bcsr<<<NB, 256, 0, stream>>>(epart, bucketCur, rowbeg, rowend, colidx, N);

    // --- h = x @ W0 + b0 (fp32 A, fused cvt, bf16 out) ---
    k_gemm_mfma<true, false><<<gemmb, 256, 0, stream>>>(nullptr, x, Wp, b0,
                                                        nullptr, nullptr, nullptr, nullptr,
                                                        hb, nullptr, N);

    // --- GAT layers (alpha dots fused into GEMM epilogue; hp stored fp8) ---
    for (int l = 0; l < L; ++l) {
        k_gemm_mfma<false, true><<<gemmb, 256, 0, stream>>>(hb, nullptr,
                                                            Wp + (size_t)(l + 1) * HF * HF, nullptr,
                                                            a_src + l * HF, a_dst + l * HF,
                                                            as_, ad_, nullptr, hp8, N);
        k_agg<<<wb4, 256, 0, stream>>>(rowbeg, rowend, colidx, hp8, as_, ad_, bl + l * HF, hb, N,
                                       (l < L - 1) ? 1 : 0);
    }

    // --- pooling + final linear ---
    k_pool<<<(N + PROWS - 1) / PROWS, 128, 0, stream>>>(hb, batch, pooled, N);
    k_final<<<GCOUNT, OUTF, 0, stream>>>(pooled, Wf, bf, out);
}

// Round 10
// 319.343 us; speedup vs baseline: 1.1434x; 1.1434x over previous
//
#include <hip/hip_runtime.h>
#include <hip/hip_bf16.h>
#include <math.h>

#define HF 128          // hidden / input feature dim
#define GCOUNT 64       // graphs in batch
#define OUTF 64         // final output features
#define NEG 0.2f        // leaky relu slope
#define CH 2048         // edges per partition block
#define BCAP 8192       // per-bucket edge capacity (expected ~4340, +50 sigma)

typedef unsigned short u16;
typedef unsigned int   u32;
typedef unsigned char  u8;
typedef short bf16x8 __attribute__((ext_vector_type(8)));
typedef float f32x4  __attribute__((ext_vector_type(4)));
typedef float f32x2  __attribute__((ext_vector_type(2)));

// fp32 -> bf16 (RNE) bit trick
__device__ __forceinline__ u16 f2b(float f) {
    u32 u = __builtin_bit_cast(u32, f);
    u32 r = (u + 0x7FFFu + ((u >> 16) & 1u)) >> 16;
    return (u16)r;
}

// ---- hardware fp8 e4m3fn codec (gfx950 OCP; v_cvt_pk_* — 2 elems/inst) ----
__device__ __forceinline__ u8 f2q(float f) {
    return (u8)(__builtin_amdgcn_cvt_pk_fp8_f32(f, f, 0, false) & 0xFF);
}

// ======================= fused pack + init =======================
// blocks 0..31: pack 4 weight matrices into MFMA B-frag order
//   P[m][(t*4+kc)*64+lane][j] = bf16(W_m[kc*32+quad*8+j][16t+(lane&15)])
// block 32: init bucketCur; blocks 33..64: zero pooled
__global__ void k_pack_init(const float* __restrict__ W0, const float* __restrict__ Wl,
                            u16* __restrict__ P, int* bucketCur, float* pooled) {
    if (blockIdx.x < 32) {
        int m = blockIdx.x >> 3;                       // 0..3: W0, Wl[0..2]
        int i = (blockIdx.x & 7) * 256 + threadIdx.x;  // 0..2047
        const float* W = (m == 0) ? W0 : Wl + (size_t)(m - 1) * HF * HF;
        u16* Pm = P + (size_t)m * HF * HF;
        int lane = i & 63, kc = (i >> 6) & 3, t = i >> 8;
        int quad = lane >> 4, col = 16 * t + (lane & 15);
        #pragma unroll
        for (int j = 0; j < 8; ++j) {
            int k = kc * 32 + quad * 8 + j;
            Pm[(size_t)i * 8 + j] = f2b(W[k * HF + col]);
        }
    } else if (blockIdx.x == 32) {
        bucketCur[threadIdx.x] = threadIdx.x * BCAP;
    } else {
        pooled[(blockIdx.x - 33) * 256 + threadIdx.x] = 0.f;
    }
}

// ======================= bucketed CSR build (fixed-capacity buckets) =======================
// bucket b = dst >> 8; bucket region = [b*BCAP, b*BCAP + cnt_b).

// single pass: LDS hist -> chunk reservation -> packed scatter (src<<8 | dst&255)
__global__ __launch_bounds__(256) void k_bpart(const int* __restrict__ esrc,
                                               const int* __restrict__ edst,
                                               int* __restrict__ bucketCur,
                                               u32* __restrict__ epart, int ne, int ntot) {
    __shared__ int cnt[256];
    __shared__ int base[256];
    int t0 = blockIdx.x * CH, t1 = min(t0 + CH, ntot);
    cnt[threadIdx.x] = 0;
    __syncthreads();
    for (int t = t0 + threadIdx.x; t < t1; t += 256) {
        int d = (t < ne) ? edst[t] : t - ne;       // tail = self loops
        atomicAdd(&cnt[d >> 8], 1);
    }
    __syncthreads();
    int c = cnt[threadIdx.x];
    base[threadIdx.x] = c ? atomicAdd(&bucketCur[threadIdx.x], c) : 0;
    cnt[threadIdx.x] = 0;
    __syncthreads();
    for (int t = t0 + threadIdx.x; t < t1; t += 256) {
        int s, d;
        if (t < ne) { s = esrc[t]; d = edst[t]; }
        else        { s = t - ne; d = s; }
        int b = d >> 8;
        int pos = base[b] + atomicAdd(&cnt[b], 1);
        epart[pos] = ((u32)s << 8) | (u32)(d & 255);
    }
}

// one block per bucket: local degree hist + scan -> rowbeg/rowend + colidx scatter
__global__ __launch_bounds__(256) void k_bcsr(const u32* __restrict__ epart,
                                              const int* __restrict__ bucketCur,
                                              int* __restrict__ rowbeg,
                                              int* __restrict__ rowend,
                                              int* __restrict__ colidx, int n) {
    __shared__ int deg[256], offs[256], curs[256], s[256];
    int b = blockIdx.x, tid = threadIdx.x;
    int e0 = b * BCAP, e1 = bucketCur[b];
    deg[tid] = 0;
    curs[tid] = 0;
    __syncthreads();
    for (int t = e0 + tid; t < e1; t += 256)
        atomicAdd(&deg[epart[t] & 255u], 1);
    __syncthreads();
    int v = deg[tid];
    s[tid] = v;
    __syncthreads();
    int acc = v;
    for (int off = 1; off < 256; off <<= 1) {
        int t = (tid >= off) ? s[tid - off] : 0;
        __syncthreads();
        acc += t;
        s[tid] = acc;
        __syncthreads();
    }
    int excl = acc - v;
    offs[tid] = excl;
    int node = (b << 8) + tid;
    if (node < n) {
        rowbeg[node] = e0 + excl;
        rowend[node] = e0 + excl + v;
    }
    __syncthreads();
    for (int t = e0 + tid; t < e1; t += 256) {
        u32 e = epart[t];
        int l = e & 255u;
        int pos = e0 + offs[l] + atomicAdd(&curs[l], 1);
        colidx[pos] = (int)(e >> 8);
    }
}

// ======================= MFMA GEMM (+bias, + optional fused alpha dots) ==========
// block = 256 (4 waves); wave w owns rows m0+16w..+15, all 128 cols (8 n-tiles).
// C/D layout: col = lane&15 (in tile), row = quad*4 + reg
// Q8: write fp8 output (layer hp); else bf16 output.
template<bool A32, bool Q8>
__global__ __launch_bounds__(256) void k_gemm_mfma(const u16* __restrict__ Ab,
                                                   const float* __restrict__ Af,
                                                   const u16* __restrict__ Bp,
                                                   const float* __restrict__ bias,
                                                   const float* __restrict__ a_s,
                                                   const float* __restrict__ a_d,
                                                   float* __restrict__ as_,
                                                   float* __restrict__ ad_,
                                                   u16* __restrict__ C,
                                                   u8* __restrict__ C8, int M) {
    int lane = threadIdx.x & 63;
    int wave = threadIdx.x >> 6;
    int quad = lane >> 4, l16 = lane & 15;
    int m0 = blockIdx.x * 64 + wave * 16;
    int arow = m0 + l16;
    bool aval = arow < M;
    const bf16x8* Av = A32 ? nullptr : (const bf16x8*)(Ab + (size_t)arow * HF);
    const bf16x8* Bv = (const bf16x8*)Bp;
    f32x4 acc[8] = {};

    #pragma unroll
    for (int kc = 0; kc < 4; ++kc) {
        bf16x8 a = {};
        if (aval) {
            if constexpr (A32) {
                const float* ap = Af + (size_t)arow * HF + kc * 32 + quad * 8;
                float4 f0 = *(const float4*)ap;
                float4 f1 = *(const float4*)(ap + 4);
                a[0] = (short)f2b(f0.x); a[1] = (short)f2b(f0.y);
                a[2] = (short)f2b(f0.z); a[3] = (short)f2b(f0.w);
                a[4] = (short)f2b(f1.x); a[5] = (short)f2b(f1.y);
                a[6] = (short)f2b(f1.z); a[7] = (short)f2b(f1.w);
            } else {
                a = Av[kc * 4 + quad];
            }
        }
        #pragma unroll
        for (int t = 0; t < 8; ++t)
            acc[t] = __builtin_amdgcn_mfma_f32_16x16x32_bf16(a, Bv[t * 256 + kc * 64 + lane],
                                                             acc[t], 0, 0, 0);
    }

    int orow0 = m0 + quad * 4;
    #pragma unroll
    for (int t = 0; t < 8; ++t) {
        float b4 = bias ? bias[t * 16 + l16] : 0.f;
        #pragma unroll
        for (int r = 0; r < 4; ++r) {
            int orow = orow0 + r;
            if (orow < M) {
                float v = acc[t][r] + b4;
                if constexpr (Q8) C8[(size_t)orow * HF + t * 16 + l16] = f2q(v);
                else              C [(size_t)orow * HF + t * 16 + l16] = f2b(v);
            }
        }
    }

    // fused attention dots (fp32 accumulators -> exact attention weights)
    if (as_) {
        float avs[8], avd[8];
        #pragma unroll
        for (int t = 0; t < 8; ++t) {
            avs[t] = a_s[t * 16 + l16];
            avd[t] = a_d[t * 16 + l16];
        }
        #pragma unroll
        for (int r = 0; r < 4; ++r) {
            float ps = 0.f, pd = 0.f;
            #pragma unroll
            for (int t = 0; t < 8; ++t) {
                ps = fmaf(acc[t][r], avs[t], ps);
                pd = fmaf(acc[t][r], avd[t], pd);
            }
            #pragma unroll
            for (int o = 1; o < 16; o <<= 1) {
                ps += __shfl_xor(ps, o);
                pd += __shfl_xor(pd, o);
            }
            int row = orow0 + r;
            if (l16 == 0 && row < M) { as_[row] = ps; ad_[row] = pd; }
        }
    }
}

// ======================= per-dst softmax aggregation (fp8 gather, HW decode) ==========
// Pass 2: half-wave per edge (32 lanes x 4B = one 128B fp8 row), 2 edges per
// load group, unroll x4. Decode: v_cvt_pk_f32_fp8 (2 elems/inst).
__global__ __launch_bounds__(256) void k_agg(const int* __restrict__ rowbeg,
                                             const int* __restrict__ rowend,
                                             const int* __restrict__ colidx,
                                             const u8* __restrict__ hp8,
                                             const float* __restrict__ as_,
                                             const float* __restrict__ ad_,
                                             const float* __restrict__ bl,
                                             u16* __restrict__ hout,
                                             int n, int relu) {
    int wave = (blockIdx.x * 256 + threadIdx.x) >> 6;
    int lane = threadIdx.x & 63;
    if (wave >= n) return;
    int beg = rowbeg[wave], end = rowend[wave];
    int deg = end - beg;
    float adi = ad_[wave];

    // lane t owns edge t (first 64)
    int  srcl = (lane < deg) ? colidx[beg + lane] : 0;
    float el = -1e30f;
    if (lane < deg) {
        float e = as_[srcl] + adi;
        el = e > 0.f ? e : NEG * e;
    }

    float m = el;
    for (int jj = beg + 64 + lane; jj < end; jj += 64) {
        float e = as_[colidx[jj]] + adi;
        e = e > 0.f ? e : NEG * e;
        m = fmaxf(m, e);
    }
    #pragma unroll
    for (int off = 32; off; off >>= 1) m = fmaxf(m, __shfl_xor(m, off));

    float ex = (lane < deg) ? __expf(el - m) : 0.f;
    float ssum = ex;
    for (int jj = beg + 64 + lane; jj < end; jj += 64) {
        float e = as_[colidx[jj]] + adi;
        e = e > 0.f ? e : NEG * e;
        ssum += __expf(e - m);
    }
    #pragma unroll
    for (int off = 32; off; off >>= 1) ssum += __shfl_xor(ssum, off);
    float inv = 1.f / ssum;
    float wl = ex * inv;        // this lane's edge weight

    // ---- pass 2 ----
    int hl = lane & 31;         // feature group: feats hl*4 .. hl*4+3
    int half = lane >> 5;       // which edge of the pair this half-wave takes
    float a0 = 0.f, a1 = 0.f, a2 = 0.f, a3 = 0.f;
    int cnt = deg < 64 ? deg : 64;
    int npair = (cnt + 1) >> 1;

    int p = 0;
    for (; p + 4 <= npair; p += 4) {
        #pragma unroll
        for (int i = 0; i < 4; ++i) {
            int e  = 2 * (p + i) + half;
            int ec = e < cnt ? e : cnt - 1;
            int   s = __shfl(srcl, ec);
            float w = (e < cnt) ? __shfl(wl, ec) : 0.f;
            u32 v = ((const u32*)(hp8 + (size_t)s * HF))[hl];
            f32x2 lo = __builtin_amdgcn_cvt_pk_f32_fp8((int)v, false);
            f32x2 hi = __builtin_amdgcn_cvt_pk_f32_fp8((int)v, true);
            a0 = fmaf(w, lo.x, a0); a1 = fmaf(w, lo.y, a1);
            a2 = fmaf(w, hi.x, a2); a3 = fmaf(w, hi.y, a3);
        }
    }
    for (; p < npair; ++p) {
        int e  = 2 * p + half;
        int ec = e < cnt ? e : cnt - 1;
        int   s = __shfl(srcl, ec);
        float w = (e < cnt) ? __shfl(wl, ec) : 0.f;
        u32 v = ((const u32*)(hp8 + (size_t)s * HF))[hl];
        f32x2 lo = __builtin_amdgcn_cvt_pk_f32_fp8((int)v, false);
        f32x2 hi = __builtin_amdgcn_cvt_pk_f32_fp8((int)v, true);
        a0 = fmaf(w, lo.x, a0); a1 = fmaf(w, lo.y, a1);
        a2 = fmaf(w, hi.x, a2); a3 = fmaf(w, hi.y, a3);
    }
    // rare deg>64 tail: half 0 only (avoids double count after combine)
    for (int jj = beg + 64; jj < end; ++jj) {
        int srcn = colidx[jj];
        float e = as_[srcn] + adi;
        e = e > 0.f ? e : NEG * e;
        float w = (half == 0) ? __expf(e - m) * inv : 0.f;
        u32 v = ((const u32*)(hp8 + (size_t)srcn * HF))[hl];
        f32x2 lo = __builtin_amdgcn_cvt_pk_f32_fp8((int)v, false);
        f32x2 hi = __builtin_amdgcn_cvt_pk_f32_fp8((int)v, true);
        a0 = fmaf(w, lo.x, a0); a1 = fmaf(w, lo.y, a1);
        a2 = fmaf(w, hi.x, a2); a3 = fmaf(w, hi.y, a3);
    }

    // combine halves
    a0 += __shfl_xor(a0, 32); a1 += __shfl_xor(a1, 32);
    a2 += __shfl_xor(a2, 32); a3 += __shfl_xor(a3, 32);

    if (half == 0) {
        float4 bb = ((const float4*)bl)[hl];
        a0 += bb.x; a1 += bb.y; a2 += bb.z; a3 += bb.w;
        if (relu) {
            a0 = fmaxf(a0, 0.f); a1 = fmaxf(a1, 0.f);
            a2 = fmaxf(a2, 0.f); a3 = fmaxf(a3, 0.f);
        }
        uint2 o;
        o.x = ((u32)f2b(a1) << 16) | (u32)f2b(a0);
        o.y = ((u32)f2b(a3) << 16) | (u32)f2b(a2);
        ((uint2*)(hout + (size_t)wave * HF))[hl] = o;
    }
}

// ======================= pooling over sorted batch (bf16 h, fp32 accum) ==========
#define PROWS 128
__global__ __launch_bounds__(128) void k_pool(const u16* __restrict__ hb,
                                              const int* __restrict__ batch,
                                              float* __restrict__ pooled, int n) {
    int r0 = blockIdx.x * PROWS;
    int r1 = min(r0 + PROWS, n);
    if (r0 >= r1) return;
    int t = threadIdx.x;
    int cur = batch[r0];
    float acc = 0.f;
    for (int i = r0; i < r1; ++i) {
        int b = batch[i];
        if (b != cur) {
            atomicAdd(&pooled[cur * HF + t], acc);
            acc = 0.f;
            cur = b;
        }
        acc += __builtin_bit_cast(float, (u32)hb[(size_t)i * HF + t] << 16);
    }
    atomicAdd(&pooled[cur * HF + t], acc);
}

__global__ void k_final(const float* __restrict__ pooled, const float* __restrict__ Wf,
                        const float* __restrict__ bf, float* __restrict__ out) {
    int g = blockIdx.x, o = threadIdx.x;   // 64 threads
    float acc = bf[o];
    #pragma unroll 8
    for (int k = 0; k < HF; ++k) acc = fmaf(pooled[g * HF + k], Wf[k * OUTF + o], acc);
    out[g * OUTF + o] = acc;
}

// ======================= launch =======================
extern "C" void kernel_launch(void* const* d_in, const int* in_sizes, int n_in,
                              void* d_out, int out_size, void* d_ws, size_t ws_size,
                              hipStream_t stream) {
    const float* x      = (const float*)d_in[0];
    const int*   edge   = (const int*)d_in[1];
    const int*   batch  = (const int*)d_in[2];
    const float* W0     = (const float*)d_in[3];
    const float* b0     = (const float*)d_in[4];
    const float* Wl     = (const float*)d_in[5];
    const float* a_src  = (const float*)d_in[6];
    const float* a_dst  = (const float*)d_in[7];
    const float* bl     = (const float*)d_in[8];
    const float* Wf     = (const float*)d_in[9];
    const float* bf     = (const float*)d_in[10];
    float* out = (float*)d_out;

    const int N  = in_sizes[2];
    const int E  = in_sizes[1] / 2;
    const int Et = E + N;
    const int L  = 3;
    const int NB = (N + 255) >> 8;               // buckets (<= 256)

    char* ws = (char*)d_ws;
    size_t off = 0;
    auto alloc = [&](size_t bytes) { char* p = ws + off; off += (bytes + 255) & ~(size_t)255; return p; };
    u16*   hb      = (u16*)alloc((size_t)N * HF * 2);
    u8*    hp8     = (u8*)alloc((size_t)N * HF);
    u16*   Wp      = (u16*)alloc((size_t)4 * HF * HF * 2);
    float* as_     = (float*)alloc((size_t)N * 4);
    float* ad_     = (float*)alloc((size_t)N * 4);
    int*   rowbeg  = (int*)alloc((size_t)N * 4);
    int*   rowend  = (int*)alloc((size_t)N * 4);
    int*   colidx  = (int*)alloc((size_t)NB * BCAP * 4);
    u32*   epart   = (u32*)alloc((size_t)NB * BCAP * 4);
    int*   bucketCur = (int*)alloc(256 * 4);
    float* pooled  = (float*)alloc((size_t)GCOUNT * HF * 4);
    (void)ws_size; (void)n_in; (void)out_size;

    const int wb4   = (N + 3) / 4;               // wave-per-node kernels
    const int gemmb = (N + 63) / 64;
    const int partb = (Et + CH - 1) / CH;

    const int* esrc = edge;
    const int* edst = edge + E;

    // --- pack weights + init bucketCur + zero pooled (one launch) ---
    k_pack_init<<<65, 256, 0, stream>>>(W0, Wl, Wp, bucketCur, pooled);

    // --- bucketed dst-CSR build (reused across all 3 layers) ---
    k_bpart<<<partb, 256, 0, stream>>>(esrc, edst, bucketCur, epart, E, Et);
    k_bcsr<<<NB, 256, 0, stream>>>(epart, bucketCur, rowbeg, rowend, colidx, N);

    // --- h = x @ W0 + b0 (fp32 A, fused cvt, bf16 out) ---
    k_gemm_mfma<true, false><<<gemmb, 256, 0, stream>>>(nullptr, x, Wp, b0,
                                                        nullptr, nullptr, nullptr, nullptr,
                                                        hb, nullptr, N);

    // --- GAT layers (alpha dots fused into GEMM epilogue; hp stored fp8) ---
    for (int l = 0; l < L; ++l) {
        k_gemm_mfma<false, true><<<gemmb, 256, 0, stream>>>(hb, nullptr,
                                                            Wp + (size_t)(l + 1) * HF * HF, nullptr,
                                                            a_src + l * HF, a_dst + l * HF,
                                                            as_, ad_, nullptr, hp8, N);
        k_agg<<<wb4, 256, 0, stream>>>(rowbeg, rowend, colidx, hp8, as_, ad_, bl + l * HF, hb, N,
                                       (l < L - 1) ? 1 : 0);
    }

    // --- pooling + final linear ---
    k_pool<<<(N + PROWS - 1) / PROWS, 128, 0, stream>>>(hb, batch, pooled, N);
    k_final<<<GCOUNT, OUTF, 0, stream>>>(pooled, Wf, bf, out);
}

// Round 12
// 317.119 us; speedup vs baseline: 1.1514x; 1.0070x over previous
//
#include <hip/hip_runtime.h>
#include <hip/hip_bf16.h>
#include <math.h>

#define HF 128          // hidden / input feature dim
#define GCOUNT 64       // graphs in batch
#define OUTF 64         // final output features
#define NEG 0.2f        // leaky relu slope
#define CH 2048         // edges per partition block
#define BCAP 8192       // per-bucket edge capacity (expected ~4340, +50 sigma)

typedef unsigned short u16;
typedef unsigned int   u32;
typedef unsigned char  u8;
typedef short bf16x8 __attribute__((ext_vector_type(8)));
typedef float f32x4  __attribute__((ext_vector_type(4)));
typedef float f32x2  __attribute__((ext_vector_type(2)));

// fp32 -> bf16 (RNE) bit trick
__device__ __forceinline__ u16 f2b(float f) {
    u32 u = __builtin_bit_cast(u32, f);
    u32 r = (u + 0x7FFFu + ((u >> 16) & 1u)) >> 16;
    return (u16)r;
}

// ---- hardware fp8 e4m3fn codec (gfx950 OCP; v_cvt_pk_* — 2 elems/inst) ----
__device__ __forceinline__ u8 f2q(float f) {
    return (u8)(__builtin_amdgcn_cvt_pk_fp8_f32(f, f, 0, false) & 0xFF);
}

// ======================= fused pack + init =======================
// blocks 0..31: pack 4 weight matrices into MFMA B-frag order
//   P[m][(t*4+kc)*64+lane][j] = bf16(W_m[kc*32+quad*8+j][16t+(lane&15)])
// block 32: init bucketCur; blocks 33..64: zero pooled
__global__ void k_pack_init(const float* __restrict__ W0, const float* __restrict__ Wl,
                            u16* __restrict__ P, int* bucketCur, float* pooled) {
    if (blockIdx.x < 32) {
        int m = blockIdx.x >> 3;                       // 0..3: W0, Wl[0..2]
        int i = (blockIdx.x & 7) * 256 + threadIdx.x;  // 0..2047
        const float* W = (m == 0) ? W0 : Wl + (size_t)(m - 1) * HF * HF;
        u16* Pm = P + (size_t)m * HF * HF;
        int lane = i & 63, kc = (i >> 6) & 3, t = i >> 8;
        int quad = lane >> 4, col = 16 * t + (lane & 15);
        #pragma unroll
        for (int j = 0; j < 8; ++j) {
            int k = kc * 32 + quad * 8 + j;
            Pm[(size_t)i * 8 + j] = f2b(W[k * HF + col]);
        }
    } else if (blockIdx.x == 32) {
        bucketCur[threadIdx.x] = threadIdx.x * BCAP;
    } else {
        pooled[(blockIdx.x - 33) * 256 + threadIdx.x] = 0.f;
    }
}

// ======================= bucketed CSR build (fixed-capacity buckets) =======================
// bucket b = dst >> 8; bucket region = [b*BCAP, b*BCAP + cnt_b).

// single pass: LDS hist -> chunk reservation -> packed scatter (src<<8 | dst&255)
__global__ __launch_bounds__(256) void k_bpart(const int* __restrict__ esrc,
                                               const int* __restrict__ edst,
                                               int* __restrict__ bucketCur,
                                               u32* __restrict__ epart, int ne, int ntot) {
    __shared__ int cnt[256];
    __shared__ int base[256];
    int t0 = blockIdx.x * CH, t1 = min(t0 + CH, ntot);
    cnt[threadIdx.x] = 0;
    __syncthreads();
    for (int t = t0 + threadIdx.x; t < t1; t += 256) {
        int d = (t < ne) ? edst[t] : t - ne;       // tail = self loops
        atomicAdd(&cnt[d >> 8], 1);
    }
    __syncthreads();
    int c = cnt[threadIdx.x];
    base[threadIdx.x] = c ? atomicAdd(&bucketCur[threadIdx.x], c) : 0;
    cnt[threadIdx.x] = 0;
    __syncthreads();
    for (int t = t0 + threadIdx.x; t < t1; t += 256) {
        int s, d;
        if (t < ne) { s = esrc[t]; d = edst[t]; }
        else        { s = t - ne; d = s; }
        int b = d >> 8;
        int pos = base[b] + atomicAdd(&cnt[b], 1);
        epart[pos] = ((u32)s << 8) | (u32)(d & 255);
    }
}

// one block per bucket: local degree hist + scan -> rowbeg/rowend + colidx scatter
__global__ __launch_bounds__(256) void k_bcsr(const u32* __restrict__ epart,
                                              const int* __restrict__ bucketCur,
                                              int* __restrict__ rowbeg,
                                              int* __restrict__ rowend,
                                              int* __restrict__ colidx, int n) {
    __shared__ int deg[256], offs[256], curs[256], s[256];
    int b = blockIdx.x, tid = threadIdx.x;
    int e0 = b * BCAP, e1 = bucketCur[b];
    deg[tid] = 0;
    curs[tid] = 0;
    __syncthreads();
    for (int t = e0 + tid; t < e1; t += 256)
        atomicAdd(&deg[epart[t] & 255u], 1);
    __syncthreads();
    int v = deg[tid];
    s[tid] = v;
    __syncthreads();
    int acc = v;
    for (int off = 1; off < 256; off <<= 1) {
        int t = (tid >= off) ? s[tid - off] : 0;
        __syncthreads();
        acc += t;
        s[tid] = acc;
        __syncthreads();
    }
    int excl = acc - v;
    offs[tid] = excl;
    int node = (b << 8) + tid;
    if (node < n) {
        rowbeg[node] = e0 + excl;
        rowend[node] = e0 + excl + v;
    }
    __syncthreads();
    for (int t = e0 + tid; t < e1; t += 256) {
        u32 e = epart[t];
        int l = e & 255u;
        int pos = e0 + offs[l] + atomicAdd(&curs[l], 1);
        colidx[pos] = (int)(e >> 8);
    }
}

// ======================= MFMA GEMM (+bias, + optional fused alpha dots) ==========
// block = 256 (4 waves); wave w owns rows m0+16w..+15, all 128 cols (8 n-tiles).
// C/D layout: col = lane&15 (in tile), row = quad*4 + reg
// Q8: write fp8 output (layer hp); else bf16 output.
template<bool A32, bool Q8>
__global__ __launch_bounds__(256) void k_gemm_mfma(const u16* __restrict__ Ab,
                                                   const float* __restrict__ Af,
                                                   const u16* __restrict__ Bp,
                                                   const float* __restrict__ bias,
                                                   const float* __restrict__ a_s,
                                                   const float* __restrict__ a_d,
                                                   float* __restrict__ as_,
                                                   float* __restrict__ ad_,
                                                   u16* __restrict__ C,
                                                   u8* __restrict__ C8, int M) {
    int lane = threadIdx.x & 63;
    int wave = threadIdx.x >> 6;
    int quad = lane >> 4, l16 = lane & 15;
    int m0 = blockIdx.x * 64 + wave * 16;
    int arow = m0 + l16;
    bool aval = arow < M;
    const bf16x8* Av = A32 ? nullptr : (const bf16x8*)(Ab + (size_t)arow * HF);
    const bf16x8* Bv = (const bf16x8*)Bp;
    f32x4 acc[8] = {};

    #pragma unroll
    for (int kc = 0; kc < 4; ++kc) {
        bf16x8 a = {};
        if (aval) {
            if constexpr (A32) {
                const float* ap = Af + (size_t)arow * HF + kc * 32 + quad * 8;
                float4 f0 = *(const float4*)ap;
                float4 f1 = *(const float4*)(ap + 4);
                a[0] = (short)f2b(f0.x); a[1] = (short)f2b(f0.y);
                a[2] = (short)f2b(f0.z); a[3] = (short)f2b(f0.w);
                a[4] = (short)f2b(f1.x); a[5] = (short)f2b(f1.y);
                a[6] = (short)f2b(f1.z); a[7] = (short)f2b(f1.w);
            } else {
                a = Av[kc * 4 + quad];
            }
        }
        #pragma unroll
        for (int t = 0; t < 8; ++t)
            acc[t] = __builtin_amdgcn_mfma_f32_16x16x32_bf16(a, Bv[t * 256 + kc * 64 + lane],
                                                             acc[t], 0, 0, 0);
    }

    int orow0 = m0 + quad * 4;
    #pragma unroll
    for (int t = 0; t < 8; ++t) {
        float b4 = bias ? bias[t * 16 + l16] : 0.f;
        #pragma unroll
        for (int r = 0; r < 4; ++r) {
            int orow = orow0 + r;
            if (orow < M) {
                float v = acc[t][r] + b4;
                if constexpr (Q8) C8[(size_t)orow * HF + t * 16 + l16] = f2q(v);
                else              C [(size_t)orow * HF + t * 16 + l16] = f2b(v);
            }
        }
    }

    // fused attention dots (fp32 accumulators -> exact attention weights)
    if (as_) {
        float avs[8], avd[8];
        #pragma unroll
        for (int t = 0; t < 8; ++t) {
            avs[t] = a_s[t * 16 + l16];
            avd[t] = a_d[t * 16 + l16];
        }
        #pragma unroll
        for (int r = 0; r < 4; ++r) {
            float ps = 0.f, pd = 0.f;
            #pragma unroll
            for (int t = 0; t < 8; ++t) {
                ps = fmaf(acc[t][r], avs[t], ps);
                pd = fmaf(acc[t][r], avd[t], pd);
            }
            #pragma unroll
            for (int o = 1; o < 16; o <<= 1) {
                ps += __shfl_xor(ps, o);
                pd += __shfl_xor(pd, o);
            }
            int row = orow0 + r;
            if (l16 == 0 && row < M) { as_[row] = ps; ad_[row] = pd; }
        }
    }
}

// ======================= per-dst softmax aggregation (fp8 gather, HW decode) ==========
// Pass 2: half-wave per edge (32 lanes x 4B = one 128B fp8 row), 2 edges per
// load group, unroll x4. Decode: v_cvt_pk_f32_fp8 (2 elems/inst).
__global__ __launch_bounds__(256) void k_agg(const int* __restrict__ rowbeg,
                                             const int* __restrict__ rowend,
                                             const int* __restrict__ colidx,
                                             const u8* __restrict__ hp8,
                                             const float* __restrict__ as_,
                                             const float* __restrict__ ad_,
                                             const float* __restrict__ bl,
                                             u16* __restrict__ hout,
                                             int n, int relu) {
    int wave = (blockIdx.x * 256 + threadIdx.x) >> 6;
    int lane = threadIdx.x & 63;
    if (wave >= n) return;
    int beg = rowbeg[wave], end = rowend[wave];
    int deg = end - beg;
    float adi = ad_[wave];

    // lane t owns edge t (first 64)
    int  srcl = (lane < deg) ? colidx[beg + lane] : 0;
    float el = -1e30f;
    if (lane < deg) {
        float e = as_[srcl] + adi;
        el = e > 0.f ? e : NEG * e;
    }

    float m = el;
    for (int jj = beg + 64 + lane; jj < end; jj += 64) {
        float e = as_[colidx[jj]] + adi;
        e = e > 0.f ? e : NEG * e;
        m = fmaxf(m, e);
    }
    #pragma unroll
    for (int off = 32; off; off >>= 1) m = fmaxf(m, __shfl_xor(m, off));

    float ex = (lane < deg) ? __expf(el - m) : 0.f;
    float ssum = ex;
    for (int jj = beg + 64 + lane; jj < end; jj += 64) {
        float e = as_[colidx[jj]] + adi;
        e = e > 0.f ? e : NEG * e;
        ssum += __expf(e - m);
    }
    #pragma unroll
    for (int off = 32; off; off >>= 1) ssum += __shfl_xor(ssum, off);
    float inv = 1.f / ssum;
    float wl = ex * inv;        // this lane's edge weight

    // ---- pass 2 ----
    int hl = lane & 31;         // feature group: feats hl*4 .. hl*4+3
    int half = lane >> 5;       // which edge of the pair this half-wave takes
    float a0 = 0.f, a1 = 0.f, a2 = 0.f, a3 = 0.f;
    int cnt = deg < 64 ? deg : 64;
    int npair = (cnt + 1) >> 1;

    int p = 0;
    for (; p + 4 <= npair; p += 4) {
        #pragma unroll
        for (int i = 0; i < 4; ++i) {
            int e  = 2 * (p + i) + half;
            int ec = e < cnt ? e : cnt - 1;
            int   s = __shfl(srcl, ec);
            float w = (e < cnt) ? __shfl(wl, ec) : 0.f;
            u32 v = ((const u32*)(hp8 + (size_t)s * HF))[hl];
            f32x2 lo = __builtin_amdgcn_cvt_pk_f32_fp8((int)v, false);
            f32x2 hi = __builtin_amdgcn_cvt_pk_f32_fp8((int)v, true);
            a0 = fmaf(w, lo.x, a0); a1 = fmaf(w, lo.y, a1);
            a2 = fmaf(w, hi.x, a2); a3 = fmaf(w, hi.y, a3);
        }
    }
    for (; p < npair; ++p) {
        int e  = 2 * p + half;
        int ec = e < cnt ? e : cnt - 1;
        int   s = __shfl(srcl, ec);
        float w = (e < cnt) ? __shfl(wl, ec) : 0.f;
        u32 v = ((const u32*)(hp8 + (size_t)s * HF))[hl];
        f32x2 lo = __builtin_amdgcn_cvt_pk_f32_fp8((int)v, false);
        f32x2 hi = __builtin_amdgcn_cvt_pk_f32_fp8((int)v, true);
        a0 = fmaf(w, lo.x, a0); a1 = fmaf(w, lo.y, a1);
        a2 = fmaf(w, hi.x, a2); a3 = fmaf(w, hi.y, a3);
    }
    // rare deg>64 tail: half 0 only (avoids double count after combine)
    for (int jj = beg + 64; jj < end; ++jj) {
        int srcn = colidx[jj];
        float e = as_[srcn] + adi;
        e = e > 0.f ? e : NEG * e;
        float w = (half == 0) ? __expf(e - m) * inv : 0.f;
        u32 v = ((const u32*)(hp8 + (size_t)srcn * HF))[hl];
        f32x2 lo = __builtin_amdgcn_cvt_pk_f32_fp8((int)v, false);
        f32x2 hi = __builtin_amdgcn_cvt_pk_f32_fp8((int)v, true);
        a0 = fmaf(w, lo.x, a0); a1 = fmaf(w, lo.y, a1);
        a2 = fmaf(w, hi.x, a2); a3 = fmaf(w, hi.y, a3);
    }

    // combine halves
    a0 += __shfl_xor(a0, 32); a1 += __shfl_xor(a1, 32);
    a2 += __shfl_xor(a2, 32); a3 += __shfl_xor(a3, 32);

    if (half == 0) {
        float4 bb = ((const float4*)bl)[hl];
        a0 += bb.x; a1 += bb.y; a2 += bb.z; a3 += bb.w;
        if (relu) {
            a0 = fmaxf(a0, 0.f); a1 = fmaxf(a1, 0.f);
            a2 = fmaxf(a2, 0.f); a3 = fmaxf(a3, 0.f);
        }
        uint2 o;
        o.x = ((u32)f2b(a1) << 16) | (u32)f2b(a0);
        o.y = ((u32)f2b(a3) << 16) | (u32)f2b(a2);
        ((uint2*)(hout + (size_t)wave * HF))[hl] = o;
    }
}

// ======================= pooling over sorted batch (bf16 h, fp32 accum) ==========
#define PROWS 128
__global__ __launch_bounds__(128) void k_pool(const u16* __restrict__ hb,
                                              const int* __restrict__ batch,
                                              float* __restrict__ pooled, int n) {
    int r0 = blockIdx.x * PROWS;
    int r1 = min(r0 + PROWS, n);
    if (r0 >= r1) return;
    int t = threadIdx.x;
    int cur = batch[r0];
    float acc = 0.f;
    for (int i = r0; i < r1; ++i) {
        int b = batch[i];
        if (b != cur) {
            atomicAdd(&pooled[cur * HF + t], acc);
            acc = 0.f;
            cur = b;
        }
        acc += __builtin_bit_cast(float, (u32)hb[(size_t)i * HF + t] << 16);
    }
    atomicAdd(&pooled[cur * HF + t], acc);
}

__global__ void k_final(const float* __restrict__ pooled, const float* __restrict__ Wf,
                        const float* __restrict__ bf, float* __restrict__ out) {
    int g = blockIdx.x, o = threadIdx.x;   // 64 threads
    float acc = bf[o];
    #pragma unroll 8
    for (int k = 0; k < HF; ++k) acc = fmaf(pooled[g * HF + k], Wf[k * OUTF + o], acc);
    out[g * OUTF + o] = acc;
}

// ======================= launch =======================
extern "C" void kernel_launch(void* const* d_in, const int* in_sizes, int n_in,
                              void* d_out, int out_size, void* d_ws, size_t ws_size,
                              hipStream_t stream) {
    const float* x      = (const float*)d_in[0];
    const int*   edge   = (const int*)d_in[1];
    const int*   batch  = (const int*)d_in[2];
    const float* W0     = (const float*)d_in[3];
    const float* b0     = (const float*)d_in[4];
    const float* Wl     = (const float*)d_in[5];
    const float* a_src  = (const float*)d_in[6];
    const float* a_dst  = (const float*)d_in[7];
    const float* bl     = (const float*)d_in[8];
    const float* Wf     = (const float*)d_in[9];
    const float* bf     = (const float*)d_in[10];
    float* out = (float*)d_out;

    const int N  = in_sizes[2];
    const int E  = in_sizes[1] / 2;
    const int Et = E + N;
    const int L  = 3;
    const int NB = (N + 255) >> 8;               // buckets (<= 256)

    char* ws = (char*)d_ws;
    size_t off = 0;
    auto alloc = [&](size_t bytes) { char* p = ws + off; off += (bytes + 255) & ~(size_t)255; return p; };
    u16*   hb      = (u16*)alloc((size_t)N * HF * 2);
    u8*    hp8     = (u8*)alloc((size_t)N * HF);
    u16*   Wp      = (u16*)alloc((size_t)4 * HF * HF * 2);
    float* as_     = (float*)alloc((size_t)N * 4);
    float* ad_     = (float*)alloc((size_t)N * 4);
    int*   rowbeg  = (int*)alloc((size_t)N * 4);
    int*   rowend  = (int*)alloc((size_t)N * 4);
    int*   colidx  = (int*)alloc((size_t)NB * BCAP * 4);
    u32*   epart   = (u32*)alloc((size_t)NB * BCAP * 4);
    int*   bucketCur = (int*)alloc(256 * 4);
    float* pooled  = (float*)alloc((size_t)GCOUNT * HF * 4);
    (void)ws_size; (void)n_in; (void)out_size;

    const int wb4   = (N + 3) / 4;               // wave-per-node kernels
    const int gemmb = (N + 63) / 64;
    const int partb = (Et + CH - 1) / CH;

    const int* esrc = edge;
    const int* edst = edge + E;

    // --- pack weights + init bucketCur + zero pooled (one launch) ---
    k_pack_init<<<65, 256, 0, stream>>>(W0, Wl, Wp, bucketCur, pooled);

    // --- bucketed dst-CSR build (reused across all 3 layers) ---
    k_bpart<<<partb, 256, 0, stream>>>(esrc, edst, bucketCur, epart, E, Et);
    k_bcsr<<<NB, 256, 0, stream>>>(epart, bucketCur, rowbeg, rowend, colidx, N);

    // --- h = x @ W0 + b0 (fp32 A, fused cvt, bf16 out) ---
    k_gemm_mfma<true, false><<<gemmb, 256, 0, stream>>>(nullptr, x, Wp, b0,
                                                        nullptr, nullptr, nullptr, nullptr,
                                                        hb, nullptr, N);

    // --- GAT layers (alpha dots fused into GEMM epilogue; hp stored fp8) ---
    for (int l = 0; l < L; ++l) {
        k_gemm_mfma<false, true><<<gemmb, 256, 0, stream>>>(hb, nullptr,
                                                            Wp + (size_t)(l + 1) * HF * HF, nullptr,
                                                            a_src + l * HF, a_dst + l * HF,
                                                            as_, ad_, nullptr, hp8, N);
        k_agg<<<wb4, 256, 0, stream>>>(rowbeg, rowend, colidx, hp8, as_, ad_, bl + l * HF, hb, N,
                                       (l < L - 1) ? 1 : 0);
    }

    // --- pooling + final linear ---
    k_pool<<<(N + PROWS - 1) / PROWS, 128, 0, stream>>>(hb, batch, pooled, N);
    k_final<<<GCOUNT, OUTF, 0, stream>>>(pooled, Wf, bf, out);
}